// Round 5
// baseline (139.398 us; speedup 1.0000x reference)
//
#include <hip/hip_runtime.h>
#include <hip/hip_bf16.h>
#include <math.h>

#define D_K  512
#define NROW 8192
#define BM   128
#define BN   128
#define BK   32          // staging unit; 16 steps, double-buffered
#define NSTEP (D_K / BK)

typedef __attribute__((ext_vector_type(8))) short bf16x8;
typedef __attribute__((ext_vector_type(4))) float f32x4;

#if __has_builtin(__builtin_amdgcn_rsqf)
#define RSQ(x) __builtin_amdgcn_rsqf(x)
#else
#define RSQ(x) rsqrtf(x)
#endif

// f32 -> bf16 round-to-nearest-even
__device__ __forceinline__ unsigned short f2bf(float f) {
    unsigned int u = __float_as_uint(f);
    unsigned int r = (u + 0x7FFFu + ((u >> 16) & 1u)) >> 16;
    return (unsigned short)r;
}

// async global->LDS, 16B per lane (wave-uniform LDS base; HW writes base + lane*16)
__device__ __forceinline__ void load_lds16(const unsigned short* g, unsigned short* l) {
    __builtin_amdgcn_global_load_lds(
        (const __attribute__((address_space(1))) unsigned int*)g,
        (__attribute__((address_space(3))) unsigned int*)l,
        16, 0, 0);
}

// ---------------- prep: f32 -> bf16 + per-row epilogue scalars ----------------
__global__ void prep_kernel(const float* __restrict__ xin, const float* __restrict__ yin,
                            unsigned short* __restrict__ xb, unsigned short* __restrict__ yb,
                            float* __restrict__ px0, float* __restrict__ px1,
                            float* __restrict__ py0, float* __restrict__ py1)
{
    const int row   = blockIdx.x;
    const int which = blockIdx.y;
    const float* src = (which ? yin : xin) + (size_t)row * D_K;
    unsigned short* dst = (which ? yb : xb) + (size_t)row * D_K;
    const int t = threadIdx.x;

    float2 v = ((const float2*)src)[t];
    ushort2 b; b.x = f2bf(v.x); b.y = f2bf(v.y);
    ((ushort2*)dst)[t] = b;

    float s = v.x * v.x + v.y * v.y;
    for (int o = 32; o > 0; o >>= 1) s += __shfl_down(s, o, 64);
    __shared__ float red[4];
    if ((t & 63) == 0) red[t >> 6] = s;
    __syncthreads();
    if (t == 0) {
        float tot = red[0] + red[1] + red[2] + red[3];
        float c0 = tot * (1.0f / D_K);
        float a0 = 1.0f + 2.0f * c0;
        float c1 = 0.636619772367581343f * asinf(2.0f * c0 / a0);
        float a1 = 1.0f + 2.0f * c1;
        if (which) {
            py0[row] = 1.0f / sqrtf(a0);
            py1[row] = 1.0f / sqrtf(a1);
        } else {
            px0[row] = 2.0f / sqrtf(a0);
            px1[row] = 2.0f / sqrtf(a1);
        }
    }
}

// one Erf layer + Dense. s = 2*rsqrt(prod), sC = (2/pi)*s. deg-7 odd asin poly
// (|ratio| < 2/3 by C-S; truncation < 1e-5 there, < 1e-7 at the observed 0.25).
// No clamp: ratio < 2c/(1+2c) < 1 structurally; bf16 noise << margin.
__device__ __forceinline__ void layer_step(float& nngp, float& ntk, float s, float sC) {
    float r = nngp * s;
    float u = r * r;
    float p = fmaf(u, 0.028420525f, 0.047746483f);
    p = fmaf(u, p, 0.106103295f);
    p = fmaf(u, p, 0.636619772f);
    float nn = r * p;
    float rv = RSQ(1.0f - u);
    ntk = fmaf(ntk, sC * rv, nn);
    nngp = nn;
}

// ---------------- main: bf16 MFMA GEMM + fused NTK epilogue ----------------
// 128x128 tile, 4 waves (2x2 of 64x64), 16x16x32 MFMA.
// T3-min counted-vmcnt pipeline: BK=32 double-buffer in 32 KiB total LDS.
// Per step: stage(t+1) -> vmcnt(4) -> s_barrier -> ds_read -> 16 MFMA -> s_barrier.
// vmcnt never 0 in the loop; raw s_barrier (no compiler drain).
__global__ void ntk_kernel(const unsigned short* __restrict__ xb,
                           const unsigned short* __restrict__ yb,
                           const float* __restrict__ px0, const float* __restrict__ px1,
                           const float* __restrict__ py0, const float* __restrict__ py1,
                           float* __restrict__ out)
{
    __shared__ unsigned short As[2][BM * BK];  // 2 x 8 KiB
    __shared__ unsigned short Bs[2][BN * BK];  // 2 x 8 KiB

    const int tid  = threadIdx.x;
    const int lane = tid & 63;
    const int wid  = tid >> 6;
    const int wr   = wid >> 1;
    const int wc   = wid & 1;

    // XCD-banded swizzle: xcd = bid&7 owns row-tile band; 8-block B-panel reuse in L2
    const int bid = blockIdx.x;
    const int xcd = bid & 7;
    const int idx = bid >> 3;
    const int by  = xcd * 8 + (idx & 7);
    const int bx  = idx >> 3;
    const int rowBase = by * BM;
    const int colBase = bx * BN;
    const int l15 = lane & 15;
    const int lg  = lane >> 4;

    const unsigned short* gA = xb + (size_t)rowBase * D_K;
    const unsigned short* gB = yb + (size_t)colBase * D_K;

    // staging geometry (per step, per matrix): 512 chunks of 16B; thread does 2.
    // chunk idx -> row = idx>>2, phys slot = idx&3 holds source chunk slot^((row>>1)&3)
    int srow[2], scol[2];
    #pragma unroll
    for (int l = 0; l < 2; l++) {
        int cidx = l * 256 + tid;
        srow[l] = cidx >> 2;
        scol[l] = ((cidx & 3) ^ ((srow[l] >> 1) & 3)) * 8;
    }

    f32x4 acc[4][4];
    #pragma unroll
    for (int m = 0; m < 4; m++)
        #pragma unroll
        for (int n = 0; n < 4; n++)
            acc[m][n] = (f32x4){0.f, 0.f, 0.f, 0.f};

    // prologue: stage step 0 into buf 0
    #pragma unroll
    for (int l = 0; l < 2; l++) {
        load_lds16(gA + (size_t)srow[l] * D_K + scol[l], &As[0][(l * 256 + wid * 64) * 8]);
        load_lds16(gB + (size_t)srow[l] * D_K + scol[l], &Bs[0][(l * 256 + wid * 64) * 8]);
    }

    #pragma unroll
    for (int t = 0; t < NSTEP; t++) {
        const int p   = t & 1;
        const int ksn = ((t + 1) * BK) & (D_K - 1);   // last step wraps: keeps vmcnt count uniform
        // stage step t+1 into buf p^1 (region-exclusive vs step-t-1 reads of p^1)
        #pragma unroll
        for (int l = 0; l < 2; l++) {
            load_lds16(gA + (size_t)srow[l] * D_K + ksn + scol[l], &As[p ^ 1][(l * 256 + wid * 64) * 8]);
            load_lds16(gB + (size_t)srow[l] * D_K + ksn + scol[l], &Bs[p ^ 1][(l * 256 + wid * 64) * 8]);
        }
        asm volatile("s_waitcnt vmcnt(4)" ::: "memory");  // step t's loads landed; t+1's in flight
        asm volatile("s_barrier" ::: "memory");

        bf16x8 af[4], bfr[4];
        #pragma unroll
        for (int m = 0; m < 4; m++) {
            int rowA = wr * 64 + m * 16 + l15;
            af[m]  = *(const bf16x8*)&As[p][rowA * BK + (lg ^ ((rowA >> 1) & 3)) * 8];
            int rowB = wc * 64 + m * 16 + l15;
            bfr[m] = *(const bf16x8*)&Bs[p][rowB * BK + (lg ^ ((rowB >> 1) & 3)) * 8];
        }
        __builtin_amdgcn_s_setprio(1);
        #pragma unroll
        for (int m = 0; m < 4; m++)
            #pragma unroll
            for (int n = 0; n < 4; n++)
                acc[m][n] = __builtin_amdgcn_mfma_f32_16x16x32_bf16(af[m], bfr[n], acc[m][n], 0, 0, 0);
        __builtin_amdgcn_s_setprio(0);
        asm volatile("s_barrier" ::: "memory");           // reads done; next step may stage into p
    }

    // fused epilogue. C/D layout: col = lane&15, row = (lane>>4)*4 + reg
    float py0v[4], py1v[4], py0C[4], py1C[4];
    int   colv[4];
    #pragma unroll
    for (int n = 0; n < 4; n++) {
        int col = colBase + wc * 64 + n * 16 + l15;
        colv[n] = col;
        py0v[n] = py0[col];
        py1v[n] = py1[col];
        py0C[n] = 0.636619772f * py0v[n];
        py1C[n] = 0.636619772f * py1v[n];
    }
    #pragma unroll
    for (int m = 0; m < 4; m++) {
        int row0 = rowBase + wr * 64 + m * 16 + lg * 4;
        #pragma unroll
        for (int j = 0; j < 4; j++) {
            int row = row0 + j;
            float a0 = px0[row], a1 = px1[row];
            #pragma unroll
            for (int n = 0; n < 4; n++) {
                float nngp = acc[m][n][j] * (1.0f / D_K);
                float ntk = nngp;
                layer_step(nngp, ntk, a0 * py0v[n], a0 * py0C[n]);
                layer_step(nngp, ntk, a1 * py1v[n], a1 * py1C[n]);
                __builtin_nontemporal_store(ntk, &out[(size_t)row * NROW + colv[n]]);
            }
        }
    }
}

extern "C" void kernel_launch(void* const* d_in, const int* in_sizes, int n_in,
                              void* d_out, int out_size, void* d_ws, size_t ws_size,
                              hipStream_t stream)
{
    const float* x = (const float*)d_in[0];
    const float* y = (const float*)d_in[1];
    float* out = (float*)d_out;

    char* ws = (char*)d_ws;
    unsigned short* xb = (unsigned short*)ws;
    unsigned short* yb = (unsigned short*)(ws + (size_t)8 * 1024 * 1024);
    float* px0 = (float*)(ws + (size_t)16 * 1024 * 1024);
    float* px1 = px0 + NROW;
    float* py0 = px1 + NROW;
    float* py1 = py0 + NROW;

    dim3 pgrid(NROW, 2);
    prep_kernel<<<pgrid, 256, 0, stream>>>(x, y, xb, yb, px0, px1, py0, py1);

    ntk_kernel<<<(NROW / BM) * (NROW / BN), 256, 0, stream>>>(xb, yb, px0, px1, py0, py1, out);
}

// Round 6
// 139.145 us; speedup vs baseline: 1.0018x; 1.0018x over previous
//
#include <hip/hip_runtime.h>
#include <hip/hip_bf16.h>
#include <math.h>

#define D_K  512
#define NROW 8192
#define BM   256
#define BN   256
#define BK   64

typedef __attribute__((ext_vector_type(8))) short bf16x8;
typedef __attribute__((ext_vector_type(4))) float f32x4;

#if __has_builtin(__builtin_amdgcn_rsqf)
#define RSQ(x) __builtin_amdgcn_rsqf(x)
#else
#define RSQ(x) rsqrtf(x)
#endif

#define BAR()    asm volatile("s_barrier" ::: "memory")
#define WAITV4() asm volatile("s_waitcnt vmcnt(4)" ::: "memory")

__device__ __forceinline__ unsigned short f2bf(float f) {
    unsigned int u = __float_as_uint(f);
    unsigned int r = (u + 0x7FFFu + ((u >> 16) & 1u)) >> 16;
    return (unsigned short)r;
}

__device__ __forceinline__ void load_lds16(const unsigned short* g, unsigned short* l) {
    __builtin_amdgcn_global_load_lds(
        (const __attribute__((address_space(1))) unsigned int*)g,
        (__attribute__((address_space(3))) unsigned int*)l,
        16, 0, 0);
}

// ---------------- prep ----------------
__global__ void prep_kernel(const float* __restrict__ xin, const float* __restrict__ yin,
                            unsigned short* __restrict__ xb, unsigned short* __restrict__ yb,
                            float* __restrict__ px0, float* __restrict__ px1,
                            float* __restrict__ py0, float* __restrict__ py1)
{
    const int row   = blockIdx.x;
    const int which = blockIdx.y;
    const float* src = (which ? yin : xin) + (size_t)row * D_K;
    unsigned short* dst = (which ? yb : xb) + (size_t)row * D_K;
    const int t = threadIdx.x;

    float2 v = ((const float2*)src)[t];
    ushort2 b; b.x = f2bf(v.x); b.y = f2bf(v.y);
    ((ushort2*)dst)[t] = b;

    float s = v.x * v.x + v.y * v.y;
    for (int o = 32; o > 0; o >>= 1) s += __shfl_down(s, o, 64);
    __shared__ float red[4];
    if ((t & 63) == 0) red[t >> 6] = s;
    __syncthreads();
    if (t == 0) {
        float tot = red[0] + red[1] + red[2] + red[3];
        float c0 = tot * (1.0f / D_K);
        float a0 = 1.0f + 2.0f * c0;
        float c1 = 0.636619772367581343f * asinf(2.0f * c0 / a0);
        float a1 = 1.0f + 2.0f * c1;
        if (which) {
            py0[row] = 1.0f / sqrtf(a0);
            py1[row] = 1.0f / sqrtf(a1);
        } else {
            px0[row] = 2.0f / sqrtf(a0);
            px1[row] = 2.0f / sqrtf(a1);
        }
    }
}

// Erf layer + Dense (deg-7 asin poly, separable rsqrt; |ratio| < 2/3 structurally)
__device__ __forceinline__ void layer_step(float& nngp, float& ntk, float s, float sC) {
    float r = nngp * s;
    float u = r * r;
    float p = fmaf(u, 0.028420525f, 0.047746483f);
    p = fmaf(u, p, 0.106103295f);
    p = fmaf(u, p, 0.636619772f);
    float nn = r * p;
    float rv = RSQ(1.0f - u);
    ntk = fmaf(ntk, sC * rv, nn);
    nngp = nn;
}

// ---------------- main: 256x256 8-phase, fully-unrolled, zero-VALU addressing ----------------
// lds dims [mat][buf][half][256*32]: ds_read imm = (buf*16384+h*8192)*2 <= 49152 < 64K.
__global__ void __launch_bounds__(512, 2)
ntk_kernel(const unsigned short* __restrict__ xb,
           const unsigned short* __restrict__ yb,
           const float* __restrict__ px0, const float* __restrict__ px1,
           const float* __restrict__ py0, const float* __restrict__ py1,
           float* __restrict__ out)
{
    __shared__ unsigned short lds[2][2][2][256 * 32];   // 128 KiB

    const int tid  = threadIdx.x;
    const int lane = tid & 63;
    const int wid  = tid >> 6;
    const int wr   = wid >> 2;          // 0..1: 128-row half
    const int wc   = wid & 3;           // 0..3: 64-col quarter
    const int l15  = lane & 15;
    const int lg   = lane >> 4;

    // XCD swizzle (1024 blocks, bijective)
    const int bid = blockIdx.x;
    const int swz = (bid & 7) * 128 + (bid >> 3);
    const int bx  = swz & 31;
    const int by  = swz >> 5;
    const int rowBase = by * BM;
    const int colBase = bx * BN;

    // ---- hoisted staging addresses (per-lane global ptrs; k advance via imm fold) ----
    // chunk c = l*512 + tid: row = c>>2, phys slot = c&3 holds source chunk slot^((row>>1)&3)
    const int c0 = tid, c1 = 512 + tid;
    const int r0 = c0 >> 2, r1 = c1 >> 2;
    const int s0 = ((c0 & 3) ^ ((r0 >> 1) & 3)) * 8;
    const int s1 = ((c1 & 3) ^ ((r1 >> 1) & 3)) * 8;
    const unsigned short* srcA0 = xb + (size_t)(rowBase + r0) * D_K + s0;
    const unsigned short* srcA1 = xb + (size_t)(rowBase + r1) * D_K + s1;
    const unsigned short* srcB0 = yb + (size_t)(colBase + r0) * D_K + s0;
    const unsigned short* srcB1 = yb + (size_t)(colBase + r1) * D_K + s1;
    const int ldsOff0 = wid * 512;          // elements (wave-uniform chunk base * 8)
    const int ldsOff1 = 4096 + wid * 512;

    // ---- hoisted ds_read fragment pointers (into [mat][0][0] frame) ----
    const unsigned short* aP[8];
    const unsigned short* bP[4];
    #pragma unroll
    for (int m = 0; m < 8; m++) {
        int rA = wr * 128 + m * 16 + l15;
        aP[m] = &lds[0][0][0][rA * 32 + ((lg ^ ((rA >> 1) & 3)) * 8)];
    }
    #pragma unroll
    for (int n = 0; n < 4; n++) {
        int rB = wc * 64 + n * 16 + l15;
        bP[n] = &lds[1][0][0][rB * 32 + ((lg ^ ((rB >> 1) & 3)) * 8)];
    }

    f32x4 acc[8][4];
    #pragma unroll
    for (int m = 0; m < 8; m++)
        #pragma unroll
        for (int n = 0; n < 4; n++)
            acc[m][n] = (f32x4){0.f, 0.f, 0.f, 0.f};

    bf16x8 af[4], bf[4];

#define STAGE_A(nb, h, ksrc) do { \
    load_lds16(srcA0 + (ksrc) * 64 + (h) * 32, &lds[0][nb][h][ldsOff0]); \
    load_lds16(srcA1 + (ksrc) * 64 + (h) * 32, &lds[0][nb][h][ldsOff1]); } while (0)
#define STAGE_B(nb, h, ksrc) do { \
    load_lds16(srcB0 + (ksrc) * 64 + (h) * 32, &lds[1][nb][h][ldsOff0]); \
    load_lds16(srcB1 + (ksrc) * 64 + (h) * 32, &lds[1][nb][h][ldsOff1]); } while (0)
#define RD_A(buf, h, mq) do { \
    af[0] = *(const bf16x8*)(aP[(mq)*4+0] + (buf)*16384 + (h)*8192); \
    af[1] = *(const bf16x8*)(aP[(mq)*4+1] + (buf)*16384 + (h)*8192); \
    af[2] = *(const bf16x8*)(aP[(mq)*4+2] + (buf)*16384 + (h)*8192); \
    af[3] = *(const bf16x8*)(aP[(mq)*4+3] + (buf)*16384 + (h)*8192); } while (0)
#define RD_B(buf, h) do { \
    bf[0] = *(const bf16x8*)(bP[0] + (buf)*16384 + (h)*8192); \
    bf[1] = *(const bf16x8*)(bP[1] + (buf)*16384 + (h)*8192); \
    bf[2] = *(const bf16x8*)(bP[2] + (buf)*16384 + (h)*8192); \
    bf[3] = *(const bf16x8*)(bP[3] + (buf)*16384 + (h)*8192); } while (0)
#define MFMA_Q(q) do { \
    _Pragma("unroll") \
    for (int mm = 0; mm < 4; mm++) \
        _Pragma("unroll") \
        for (int n = 0; n < 4; n++) \
            acc[(q)*4+mm][n] = __builtin_amdgcn_mfma_f32_16x16x32_bf16(af[mm], bf[n], acc[(q)*4+mm][n], 0, 0, 0); } while (0)

#define TILE(buf, nb, ksrc) do { \
    /* PH1: h0, A-quadrant 0 */ \
    RD_A(buf, 0, 0); RD_B(buf, 0); \
    STAGE_A(nb, 0, ksrc); \
    BAR(); \
    __builtin_amdgcn_s_setprio(1); MFMA_Q(0); __builtin_amdgcn_s_setprio(0); \
    BAR(); \
    /* PH2: h0, A-quadrant 1 */ \
    RD_A(buf, 0, 1); \
    STAGE_B(nb, 0, ksrc); \
    BAR(); \
    __builtin_amdgcn_s_setprio(1); MFMA_Q(1); __builtin_amdgcn_s_setprio(0); \
    WAITV4(); \
    BAR(); \
    /* PH3: h1, A-quadrant 0 */ \
    RD_A(buf, 1, 0); RD_B(buf, 1); \
    STAGE_A(nb, 1, ksrc); \
    BAR(); \
    __builtin_amdgcn_s_setprio(1); MFMA_Q(0); __builtin_amdgcn_s_setprio(0); \
    BAR(); \
    /* PH4: h1, A-quadrant 1 */ \
    RD_A(buf, 1, 1); \
    STAGE_B(nb, 1, ksrc); \
    BAR(); \
    __builtin_amdgcn_s_setprio(1); MFMA_Q(1); __builtin_amdgcn_s_setprio(0); \
    WAITV4(); \
    BAR(); \
} while (0)

    // prologue: stage tile 0 (A-h0, B-h0, A-h1, B-h1); retire the h0 pair; sync
    STAGE_A(0, 0, 0); STAGE_B(0, 0, 0); STAGE_A(0, 1, 0); STAGE_B(0, 1, 0);
    WAITV4();
    BAR();

    TILE(0, 1, 1);
    TILE(1, 0, 2);
    TILE(0, 1, 3);
    TILE(1, 0, 4);
    TILE(0, 1, 5);
    TILE(1, 0, 6);
    TILE(0, 1, 7);
    TILE(1, 0, 0);   // last tile wrap-stages tile-0 source (in-bounds, unread)

    // ---------------- fused epilogue ----------------
    float py0v[4], py1v[4], py0C[4], py1C[4];
    int   colv[4];
    #pragma unroll
    for (int n = 0; n < 4; n++) {
        int col = colBase + wc * 64 + n * 16 + l15;
        colv[n] = col;
        py0v[n] = py0[col];
        py1v[n] = py1[col];
        py0C[n] = 0.636619772f * py0v[n];
        py1C[n] = 0.636619772f * py1v[n];
    }
    #pragma unroll
    for (int m = 0; m < 8; m++) {
        int row0 = rowBase + wr * 128 + m * 16 + lg * 4;
        #pragma unroll
        for (int j = 0; j < 4; j++) {
            int row = row0 + j;
            float a0 = px0[row], a1 = px1[row];
            #pragma unroll
            for (int n = 0; n < 4; n++) {
                float nngp = acc[m][n][j] * (1.0f / D_K);
                float ntk = nngp;
                layer_step(nngp, ntk, a0 * py0v[n], a0 * py0C[n]);
                layer_step(nngp, ntk, a1 * py1v[n], a1 * py1C[n]);
                __builtin_nontemporal_store(ntk, &out[(size_t)row * NROW + colv[n]]);
            }
        }
    }
}

extern "C" void kernel_launch(void* const* d_in, const int* in_sizes, int n_in,
                              void* d_out, int out_size, void* d_ws, size_t ws_size,
                              hipStream_t stream)
{
    const float* x = (const float*)d_in[0];
    const float* y = (const float*)d_in[1];
    float* out = (float*)d_out;

    char* ws = (char*)d_ws;
    unsigned short* xb = (unsigned short*)ws;
    unsigned short* yb = (unsigned short*)(ws + (size_t)8 * 1024 * 1024);
    float* px0 = (float*)(ws + (size_t)16 * 1024 * 1024);
    float* px1 = px0 + NROW;
    float* py0 = px1 + NROW;
    float* py1 = py0 + NROW;

    dim3 pgrid(NROW, 2);
    prep_kernel<<<pgrid, 256, 0, stream>>>(x, y, xb, yb, px0, px1, py0, py1);

    ntk_kernel<<<(NROW / BM) * (NROW / BN), 512, 0, stream>>>(xb, yb, px0, px1, py0, py1, out);
}